// Round 12
// baseline (190.068 us; speedup 1.0000x reference)
//
#include <hip/hip_runtime.h>

#define N_NODES 100000
#define N_EDGES 1600000
#define D_IN 128
#define D_HID 64
#define BN_EPS 1e-5f

#define BUCKET_SHIFT 7
#define BUCKET_W 128                                    // nodes per bucket
#define N_BUCKETS ((N_NODES + BUCKET_W - 1) / BUCKET_W) // 782
#define BCAP 4096                                       // fixed per-bucket capacity (mean 2046, sigma 45)
#define N_BIN_BLOCKS 250
#define EDGES_PER_BLOCK (N_EDGES / N_BIN_BLOCKS)        // 6400 exact, 16B-aligned
#define E4_PER_BLOCK (EDGES_PER_BLOCK / 4)              // 1600 int4

typedef __attribute__((ext_vector_type(8))) short bf16x8;
typedef __attribute__((ext_vector_type(4))) float f32x4;
typedef __attribute__((ext_vector_type(8))) _Float16 f16x8;

__device__ __forceinline__ ushort f2bf(float f) {       // RTNE fp32 -> bf16
    unsigned u = __float_as_uint(f);
    u += 0x7FFF + ((u >> 16) & 1);
    return (ushort)(u >> 16);
}

// --- 1. fused bin: single global read; entries+buckets staged in LDS ---
// Pass1 reads col/row once (int4), stages packed entry + bucket id in LDS
// while counting; pass2 scatters from LDS (no 12.8MB re-read, no re-decode).
__global__ __launch_bounds__(1024) void bin_scatter_kernel(const int* __restrict__ row,
                                                           const int* __restrict__ col,
                                                           int* __restrict__ bcursor,
                                                           int* __restrict__ binned) {
    __shared__ int hist[N_BUCKETS];                      // 3.1 KB
    __shared__ int lbase[N_BUCKETS];                     // 3.1 KB
    __shared__ int ent[EDGES_PER_BLOCK];                 // 25.6 KB packed entries
    __shared__ ushort ebk[EDGES_PER_BLOCK];              // 12.8 KB bucket ids
    const int t = threadIdx.x;
    for (int i = t; i < N_BUCKETS; i += 1024) hist[i] = 0;
    __syncthreads();
    const int e0 = blockIdx.x * EDGES_PER_BLOCK;
    const int4* __restrict__ colv = (const int4*)(col + e0);
    const int4* __restrict__ rowv = (const int4*)(row + e0);
    for (int j4 = t; j4 < E4_PER_BLOCK; j4 += 1024) {    // single read pass
        int4 c = colv[j4];
        int4 r = rowv[j4];
        int cc[4] = {c.x, c.y, c.z, c.w};
        int rr[4] = {r.x, r.y, r.z, r.w};
        #pragma unroll
        for (int k = 0; k < 4; ++k) {
            int b = cc[k] >> BUCKET_SHIFT;
            int idx = 4 * j4 + k;
            ent[idx] = ((cc[k] & (BUCKET_W - 1)) << 17) | rr[k];
            ebk[idx] = (ushort)b;
            atomicAdd(&hist[b], 1);
        }
    }
    __syncthreads();
    for (int i = t; i < N_BUCKETS; i += 1024) {
        int h = hist[i];
        lbase[i] = h ? (i * BCAP + atomicAdd(&bcursor[i], h)) : 0;
        hist[i] = 0;   // local rank cursor
    }
    __syncthreads();
    for (int j = t; j < EDGES_PER_BLOCK; j += 1024) {    // scatter from LDS
        int b = ebk[j];
        int rank = atomicAdd(&hist[b], 1);
        binned[lbase[b] + rank] = ent[j];
    }
}

// --- 2. fused bucket sort + MFMA gemm for the bucket's own 128 nodes ---
// Sort = R7-verified bucket_csr. Gemm = R9-verified 2-half MFMA body; dinv
// straight from LDS. NEW: rnd-0 x tile prefetched into registers before the
// sort so its HBM latency hides under the whole sort section.
union CsrGemmSh {
    struct { int eb[BCAP]; int cl[BCAP]; } s;            // 32 KB (sort)
    ushort xb[2][16 * 136];                              // 8.7 KB (gemm, reused)
};
__global__ __launch_bounds__(512) void csr_gemm_kernel(const int* __restrict__ binned,
                                                       const int* __restrict__ bcursor,
                                                       const float* __restrict__ x,
                                                       const float* __restrict__ W,
                                                       int* __restrict__ csr_src,
                                                       int2* __restrict__ rs2,
                                                       float* __restrict__ dinv,
                                                       ushort* __restrict__ h_s) {
    __shared__ CsrGemmSh sh;
    __shared__ int hist[BUCKET_W];
    __shared__ int cursor[BUCKET_W];
    __shared__ float dsh[BUCKET_W];
    const int b = blockIdx.x;
    const int t = threadIdx.x;

    // W fragment + rnd-0 x tile loads issued up front: independent of sort.
    const int l = t & 63;
    const int wv = (t >> 6) & 3;
    const int q = l >> 4;
    const int m = l & 15;
    const int hh = t >> 8;          // half 0/1 (16 nodes each)
    const int tt = t & 255;
    bf16x8 bf[4];               // B[k=32s+8q+j][n=16wv+m]
    {
        const int n = wv * 16 + m;
        #pragma unroll
        for (int s = 0; s < 4; ++s)
            #pragma unroll
            for (int j = 0; j < 8; ++j)
                bf[s][j] = (short)f2bf(W[(32 * s + 8 * q + j) * D_HID + n]);
    }
    float4 px[2];               // rnd-0 staging rows (2 float4/thread)
    {
        #pragma unroll
        for (int ii = 0; ii < 2; ++ii) {
            int i = tt + ii * 256;
            int r = i >> 5, c4 = i & 31;
            int nr = b * BUCKET_W + hh * 16 + r;
            if (nr >= N_NODES) nr = N_NODES - 1;         // bucket 781 tail clamp
            px[ii] = *(const float4*)&x[(size_t)nr * D_IN + c4 * 4];
        }
    }

    // ---- sort section (R7 bucket_csr verbatim) ----
    if (t < BUCKET_W) hist[t] = 0;
    __syncthreads();
    const int s = b * BCAP;
    const int cnt = bcursor[b];
    const int n4 = (cnt + 3) >> 2;
    const int4* __restrict__ binv = (const int4*)(binned + s);
    for (int i4 = t; i4 < n4; i4 += 512) {               // stage + histogram
        int4 v = binv[i4];
        int vv[4] = {v.x, v.y, v.z, v.w};
        #pragma unroll
        for (int k = 0; k < 4; ++k) {
            int idx = 4 * i4 + k;
            if (idx < cnt) {
                sh.s.eb[idx] = vv[k];
                atomicAdd(&hist[vv[k] >> 17], 1);
            }
        }
    }
    __syncthreads();
    if (t < BUCKET_W) cursor[t] = hist[t];
    for (int off = 1; off < BUCKET_W; off <<= 1) {       // inclusive scan
        __syncthreads();
        int add = (t >= off && t < BUCKET_W) ? cursor[t - off] : 0;
        __syncthreads();
        if (t < BUCKET_W) cursor[t] += add;
    }
    __syncthreads();
    int excl = (t < BUCKET_W) ? (cursor[t] - hist[t]) : 0;
    __syncthreads();
    if (t < BUCKET_W) cursor[t] = excl;
    {
        const int node = b * BUCKET_W + t;
        if (t < BUCKET_W) {
            float dn = rsqrtf(1.0f + (float)hist[t]);
            dsh[t] = dn;
            if (node < N_NODES) {
                rs2[node] = make_int2(s + excl, hist[t]);
                dinv[node] = dn;
            }
        }
    }
    __syncthreads();
    for (int i = t; i < cnt; i += 512) {                 // sort scatter in LDS
        int p = sh.s.eb[i];
        int pos = atomicAdd(&cursor[p >> 17], 1);
        sh.s.cl[pos] = p & 0x1FFFF;
    }
    __syncthreads();
    {
        int4* __restrict__ csrv = (int4*)(csr_src + s);  // coalesced dump
        const int4* __restrict__ clv = (const int4*)sh.s.cl;
        for (int i4 = t; i4 < n4; i4 += 512)
            csrv[i4] = clv[i4];
    }
    __syncthreads();   // cl dead; xb may now overwrite union

    // ---- gemm section: h_s = dinv * (x @ W1) for nodes b*128 .. b*128+127 ----
    #pragma unroll
    for (int rnd = 0; rnd < 4; ++rnd) {                  // 4 rounds x 32 nodes
        const int node0 = b * BUCKET_W + rnd * 32 + hh * 16;
        __syncthreads();
        if (rnd == 0) {                                  // from prefetch registers
            #pragma unroll
            for (int ii = 0; ii < 2; ++ii) {
                int i = tt + ii * 256;
                int r = i >> 5, c4 = i & 31;
                float4 v = px[ii];
                ushort4 u = make_ushort4(f2bf(v.x), f2bf(v.y), f2bf(v.z), f2bf(v.w));
                *(ushort4*)&sh.xb[hh][r * 136 + c4 * 4] = u;
            }
        } else {
            for (int i = tt; i < 512; i += 256) {        // 16 rows x 32 float4
                int r = i >> 5, c4 = i & 31;
                int nr = node0 + r;
                if (nr >= N_NODES) nr = N_NODES - 1;     // bucket 781 tail clamp
                float4 v = *(const float4*)&x[(size_t)nr * D_IN + c4 * 4];
                ushort4 u = make_ushort4(f2bf(v.x), f2bf(v.y), f2bf(v.z), f2bf(v.w));
                *(ushort4*)&sh.xb[hh][r * 136 + c4 * 4] = u;
            }
        }
        __syncthreads();
        f32x4 acc = {0.f, 0.f, 0.f, 0.f};
        #pragma unroll
        for (int ks = 0; ks < 4; ++ks) {
            bf16x8 af = *(const bf16x8*)&sh.xb[hh][m * 136 + 32 * ks + 8 * q];
            acc = __builtin_amdgcn_mfma_f32_16x16x32_bf16(af, bf[ks], acc, 0, 0, 0);
        }
        #pragma unroll
        for (int r = 0; r < 4; ++r) {
            int node = node0 + q * 4 + r;    // C/D: row=(lane>>4)*4+reg, col=lane&15
            if (node < N_NODES) {
                _Float16 hv = (_Float16)(acc[r] * dsh[node - b * BUCKET_W]);
                h_s[node * D_HID + wv * 16 + m] = __builtin_bit_cast(unsigned short, hv);
            }
        }
    }
}

// --- 3. fused aggregate + bias/BN/relu + fc projection (R7-verified) ---
__global__ __launch_bounds__(256) void aggregate_kernel(const ushort* __restrict__ h_s,
                                                        const float* __restrict__ dinv,
                                                        const int2* __restrict__ rs2,
                                                        const int* __restrict__ csr_src,
                                                        const float* __restrict__ b1,
                                                        const float* __restrict__ gamma,
                                                        const float* __restrict__ beta,
                                                        const float* __restrict__ mean,
                                                        const float* __restrict__ var,
                                                        const float* __restrict__ Wfc,
                                                        float4* __restrict__ uv) {
    const f16x8* __restrict__ hsv = (const f16x8*)h_s;   // [node][8] octets
    const int wvid = (blockIdx.x * 256 + threadIdx.x) >> 6; // wave id (grid exact)
    const int lane = threadIdx.x & 63;
    const int oct = lane >> 3;                           // node slot 0..7
    const int ol = lane & 7;                             // feature octet 0..7
    const int n = wvid * 8 + oct;                        // node
    f16x8 acc = hsv[n * 8 + ol];                         // self-loop (pre-scaled)
    const int2 rs = rs2[n];
    const int start = rs.x;
    const int cnt = rs.y;
    int j = 0;
    for (; j + 8 <= cnt; j += 8) {                       // 8 gathers in flight/octet
        int i0 = csr_src[start + j + 0];
        int i1 = csr_src[start + j + 1];
        int i2 = csr_src[start + j + 2];
        int i3 = csr_src[start + j + 3];
        int i4 = csr_src[start + j + 4];
        int i5 = csr_src[start + j + 5];
        int i6 = csr_src[start + j + 6];
        int i7 = csr_src[start + j + 7];
        f16x8 v0 = hsv[i0 * 8 + ol];
        f16x8 v1 = hsv[i1 * 8 + ol];
        f16x8 v2 = hsv[i2 * 8 + ol];
        f16x8 v3 = hsv[i3 * 8 + ol];
        f16x8 v4 = hsv[i4 * 8 + ol];
        f16x8 v5 = hsv[i5 * 8 + ol];
        f16x8 v6 = hsv[i6 * 8 + ol];
        f16x8 v7 = hsv[i7 * 8 + ol];
        acc += v0; acc += v1; acc += v2; acc += v3;
        acc += v4; acc += v5; acc += v6; acc += v7;
    }
    for (; j + 4 <= cnt; j += 4) {
        int i0 = csr_src[start + j + 0];
        int i1 = csr_src[start + j + 1];
        int i2 = csr_src[start + j + 2];
        int i3 = csr_src[start + j + 3];
        f16x8 v0 = hsv[i0 * 8 + ol];
        f16x8 v1 = hsv[i1 * 8 + ol];
        f16x8 v2 = hsv[i2 * 8 + ol];
        f16x8 v3 = hsv[i3 * 8 + ol];
        acc += v0; acc += v1; acc += v2; acc += v3;
    }
    for (; j + 2 <= cnt; j += 2) {
        int i0 = csr_src[start + j + 0];
        int i1 = csr_src[start + j + 1];
        f16x8 v0 = hsv[i0 * 8 + ol];
        f16x8 v1 = hsv[i1 * 8 + ol];
        acc += v0; acc += v1;
    }
    if (j < cnt)
        acc += hsv[csr_src[start + j] * 8 + ol];
    // epilogue: lane handles features f0..f0+7 of node n
    const float dn = dinv[n];
    const int f0 = 8 * ol;
    float a[8];
    #pragma unroll
    for (int k = 0; k < 8; ++k) a[k] = (float)acc[k] * dn;
    float bb[8], mu[8], vr[8], gm[8], bt[8];
    *(float4*)&bb[0] = *(const float4*)&b1[f0];    *(float4*)&bb[4] = *(const float4*)&b1[f0 + 4];
    *(float4*)&mu[0] = *(const float4*)&mean[f0];  *(float4*)&mu[4] = *(const float4*)&mean[f0 + 4];
    *(float4*)&vr[0] = *(const float4*)&var[f0];   *(float4*)&vr[4] = *(const float4*)&var[f0 + 4];
    *(float4*)&gm[0] = *(const float4*)&gamma[f0]; *(float4*)&gm[4] = *(const float4*)&gamma[f0 + 4];
    *(float4*)&bt[0] = *(const float4*)&beta[f0];  *(float4*)&bt[4] = *(const float4*)&beta[f0 + 4];
    #pragma unroll
    for (int k = 0; k < 8; ++k) {
        float v = fmaxf(a[k] + bb[k], 0.f);
        a[k] = fmaxf((v - mu[k]) * rsqrtf(vr[k] + BN_EPS) * gm[k] + bt[k], 0.f);
    }
    // Wfc[128][2]: top rows f0..f0+7 -> p0/p1; bottom rows 64+f0.. -> p2/p3
    float wt[16], wb[16];
    #pragma unroll
    for (int k = 0; k < 4; ++k) {
        *(float4*)&wt[4 * k] = *(const float4*)&Wfc[2 * f0 + 4 * k];
        *(float4*)&wb[4 * k] = *(const float4*)&Wfc[128 + 2 * f0 + 4 * k];
    }
    float p0 = 0.f, p1 = 0.f, p2 = 0.f, p3 = 0.f;
    #pragma unroll
    for (int k = 0; k < 8; ++k) {
        p0 += a[k] * wt[2 * k];
        p1 += a[k] * wt[2 * k + 1];
        p2 += a[k] * wb[2 * k];
        p3 += a[k] * wb[2 * k + 1];
    }
    #pragma unroll
    for (int off = 4; off > 0; off >>= 1) {              // reduce within octet
        p0 += __shfl_xor(p0, off, 64);
        p1 += __shfl_xor(p1, off, 64);
        p2 += __shfl_xor(p2, off, 64);
        p3 += __shfl_xor(p3, off, 64);
    }
    if (ol == 0) uv[n] = make_float4(p0, p1, p2, p3);
}

// --- 4. edge head: 2 edges/thread; out = uv[row].xy + uv[col].zw + bfc ---
__global__ __launch_bounds__(256) void edgeout_kernel(const int* __restrict__ row,
                                                      const int* __restrict__ col,
                                                      const float4* __restrict__ uv,
                                                      const float* __restrict__ bfc,
                                                      float2* __restrict__ out) {
    int i = blockIdx.x * 256 + threadIdx.x;          // over N_EDGES/2 (grid exact)
    int e = i * 2;
    int2 rr = *(const int2*)&row[e];
    int2 cc = *(const int2*)&col[e];
    float4 a0 = uv[rr.x];
    float4 b0 = uv[cc.x];
    float4 a1 = uv[rr.y];
    float4 b1 = uv[cc.y];
    float c0 = bfc[0], c1 = bfc[1];
    float4 o = make_float4(a0.x + b0.z + c0, a0.y + b0.w + c1,
                           a1.x + b1.z + c0, a1.y + b1.w + c1);
    *(float4*)&out[e] = o;
}

extern "C" void kernel_launch(void* const* d_in, const int* in_sizes, int n_in,
                              void* d_out, int out_size, void* d_ws, size_t ws_size,
                              hipStream_t stream) {
    const float* x     = (const float*)d_in[0];
    const int*   ei    = (const int*)d_in[1];
    const int*   row   = ei;             // sources
    const int*   col   = ei + N_EDGES;   // targets
    const float* W1    = (const float*)d_in[2];
    const float* b1    = (const float*)d_in[3];
    const float* gamma = (const float*)d_in[4];
    const float* beta  = (const float*)d_in[5];
    const float* mean  = (const float*)d_in[6];
    const float* var   = (const float*)d_in[7];
    const float* Wfc   = (const float*)d_in[8];
    const float* bfc   = (const float*)d_in[9];
    float2* out = (float2*)d_out;

    char* ws = (char*)d_ws;
    size_t off = 0;
    ushort* h_s      = (ushort*)(ws + off); off += (size_t)N_NODES * D_HID * 2;    // 12.8 MB
    int*   binned    = (int*)(ws + off);    off += (size_t)N_BUCKETS * BCAP * 4;   // 12.8 MB
    int*   csr_src   = (int*)(ws + off);    off += (size_t)N_BUCKETS * BCAP * 4;   // 12.8 MB
    int*   bcursor   = (int*)(ws + off);    off += ((size_t)N_BUCKETS * 4 + 15) & ~(size_t)15;
    int2*  rs2       = (int2*)(ws + off);   off += (size_t)N_NODES * 8;            // 0.8 MB
    float* dinv      = (float*)(ws + off);  off += (size_t)N_NODES * 4;
    float4* uv       = (float4*)(ws + off); off += (size_t)N_NODES * 16;           // 1.6 MB

    hipMemsetAsync(bcursor, 0, N_BUCKETS * sizeof(int), stream);
    bin_scatter_kernel<<<N_BIN_BLOCKS, 1024, 0, stream>>>(row, col, bcursor, binned);
    csr_gemm_kernel<<<N_BUCKETS, 512, 0, stream>>>(binned, bcursor, x, W1,
                                                   csr_src, rs2, dinv, h_s);
    aggregate_kernel<<<N_NODES / 32, 256, 0, stream>>>(h_s, dinv, rs2, csr_src,
                                                       b1, gamma, beta, mean, var,
                                                       Wfc, uv);
    edgeout_kernel<<<N_EDGES / 512, 256, 0, stream>>>(row, col, uv, bfc, out);
}

// Round 13
// 185.787 us; speedup vs baseline: 1.0230x; 1.0230x over previous
//
#include <hip/hip_runtime.h>

#define N_NODES 100000
#define N_EDGES 1600000
#define D_IN 128
#define D_HID 64
#define BN_EPS 1e-5f

#define BUCKET_SHIFT 7
#define BUCKET_W 128                                    // nodes per bucket
#define N_BUCKETS ((N_NODES + BUCKET_W - 1) / BUCKET_W) // 782
#define BCAP 4096                                       // fixed per-bucket capacity (mean 2046, sigma 45)
#define N_BIN_BLOCKS 250
#define EDGES_PER_BLOCK (N_EDGES / N_BIN_BLOCKS)        // 6400 exact, 16B-aligned
#define E4_PER_BLOCK (EDGES_PER_BLOCK / 4)              // 1600 int4

typedef __attribute__((ext_vector_type(8))) short bf16x8;
typedef __attribute__((ext_vector_type(4))) float f32x4;
typedef __attribute__((ext_vector_type(8))) _Float16 f16x8;

__device__ __forceinline__ ushort f2bf(float f) {       // RTNE fp32 -> bf16
    unsigned u = __float_as_uint(f);
    u += 0x7FFF + ((u >> 16) & 1);
    return (ushort)(u >> 16);
}

// --- 1. fused bin: LDS count -> reserve -> scatter; int4 edge reads (R10-verified) ---
__global__ __launch_bounds__(1024) void bin_scatter_kernel(const int* __restrict__ row,
                                                           const int* __restrict__ col,
                                                           int* __restrict__ bcursor,
                                                           int* __restrict__ binned) {
    __shared__ int hist[N_BUCKETS];
    __shared__ int lbase[N_BUCKETS];
    const int t = threadIdx.x;
    for (int i = t; i < N_BUCKETS; i += 1024) hist[i] = 0;
    __syncthreads();
    const int e0 = blockIdx.x * EDGES_PER_BLOCK;
    const int4* __restrict__ colv = (const int4*)(col + e0);
    const int4* __restrict__ rowv = (const int4*)(row + e0);
    for (int j4 = t; j4 < E4_PER_BLOCK; j4 += 1024) {
        int4 c = colv[j4];
        atomicAdd(&hist[c.x >> BUCKET_SHIFT], 1);
        atomicAdd(&hist[c.y >> BUCKET_SHIFT], 1);
        atomicAdd(&hist[c.z >> BUCKET_SHIFT], 1);
        atomicAdd(&hist[c.w >> BUCKET_SHIFT], 1);
    }
    __syncthreads();
    for (int i = t; i < N_BUCKETS; i += 1024) {
        int h = hist[i];
        lbase[i] = h ? (i * BCAP + atomicAdd(&bcursor[i], h)) : 0;
        hist[i] = 0;   // local rank cursor
    }
    __syncthreads();
    for (int j4 = t; j4 < E4_PER_BLOCK; j4 += 1024) {    // col re-read is L2-hot
        int4 c = colv[j4];
        int4 r = rowv[j4];
        int cc[4] = {c.x, c.y, c.z, c.w};
        int rr[4] = {r.x, r.y, r.z, r.w};
        #pragma unroll
        for (int k = 0; k < 4; ++k) {
            int b = cc[k] >> BUCKET_SHIFT;
            int rank = atomicAdd(&hist[b], 1);
            binned[lbase[b] + rank] = ((cc[k] & (BUCKET_W - 1)) << 17) | rr[k];
        }
    }
}

// --- 2. fused bucket sort + MFMA gemm for the bucket's own 128 nodes ---
// Sort = R7-verified bucket_csr BUT the 128-entry scan is now a 2-wave
// __shfl_up scan (2 barriers instead of 16 — R12 diagnosed the barrier
// chain as the binding constraint). Gemm = R9-verified 2-half MFMA body.
union CsrGemmSh {
    struct { int eb[BCAP]; int cl[BCAP]; } s;            // 32 KB (sort)
    ushort xb[2][16 * 136];                              // 8.7 KB (gemm, reused)
};
__global__ __launch_bounds__(512) void csr_gemm_kernel(const int* __restrict__ binned,
                                                       const int* __restrict__ bcursor,
                                                       const float* __restrict__ x,
                                                       const float* __restrict__ W,
                                                       int* __restrict__ csr_src,
                                                       int2* __restrict__ rs2,
                                                       float* __restrict__ dinv,
                                                       ushort* __restrict__ h_s) {
    __shared__ CsrGemmSh sh;
    __shared__ int hist[BUCKET_W];
    __shared__ int cursor[BUCKET_W];
    __shared__ float dsh[BUCKET_W];
    __shared__ int wsum[2];
    const int b = blockIdx.x;
    const int t = threadIdx.x;

    // W fragment loads issued up front: independent of sort, overlaps it.
    const int l = t & 63;
    const int wv = (t >> 6) & 3;
    const int q = l >> 4;
    const int m = l & 15;
    bf16x8 bf[4];               // B[k=32s+8q+j][n=16wv+m]
    {
        const int n = wv * 16 + m;
        #pragma unroll
        for (int s = 0; s < 4; ++s)
            #pragma unroll
            for (int j = 0; j < 8; ++j)
                bf[s][j] = (short)f2bf(W[(32 * s + 8 * q + j) * D_HID + n]);
    }

    // ---- sort section ----
    if (t < BUCKET_W) hist[t] = 0;
    __syncthreads();
    const int s = b * BCAP;
    const int cnt = bcursor[b];
    const int n4 = (cnt + 3) >> 2;
    const int4* __restrict__ binv = (const int4*)(binned + s);
    for (int i4 = t; i4 < n4; i4 += 512) {               // stage + histogram
        int4 v = binv[i4];
        int vv[4] = {v.x, v.y, v.z, v.w};
        #pragma unroll
        for (int k = 0; k < 4; ++k) {
            int idx = 4 * i4 + k;
            if (idx < cnt) {
                sh.s.eb[idx] = vv[k];
                atomicAdd(&hist[vv[k] >> 17], 1);
            }
        }
    }
    __syncthreads();
    // 128-entry inclusive scan: per-wave shfl scan (waves 0,1) + fixup
    {
        int val = (t < BUCKET_W) ? hist[t] : 0;
        #pragma unroll
        for (int off = 1; off < 64; off <<= 1) {
            int up = __shfl_up(val, off, 64);
            if ((t & 63) >= off) val += up;
        }
        if (t < BUCKET_W && (t & 63) == 63) wsum[t >> 6] = val;
        __syncthreads();
        if (t >= 64 && t < BUCKET_W) val += wsum[0];
        if (t < BUCKET_W) {
            int excl = val - hist[t];                    // exclusive prefix
            cursor[t] = excl;
            float dn = rsqrtf(1.0f + (float)hist[t]);
            dsh[t] = dn;
            const int node = b * BUCKET_W + t;
            if (node < N_NODES) {
                rs2[node] = make_int2(s + excl, hist[t]);
                dinv[node] = dn;
            }
        }
    }
    __syncthreads();
    for (int i = t; i < cnt; i += 512) {                 // sort scatter in LDS
        int p = sh.s.eb[i];
        int pos = atomicAdd(&cursor[p >> 17], 1);
        sh.s.cl[pos] = p & 0x1FFFF;
    }
    __syncthreads();
    {
        int4* __restrict__ csrv = (int4*)(csr_src + s);  // coalesced dump
        const int4* __restrict__ clv = (const int4*)sh.s.cl;
        for (int i4 = t; i4 < n4; i4 += 512)
            csrv[i4] = clv[i4];
    }
    __syncthreads();   // cl dead; xb may now overwrite union

    // ---- gemm section: h_s = dinv * (x @ W1) for nodes b*128 .. b*128+127 ----
    const int hh = t >> 8;          // half 0/1 (16 nodes each)
    const int tt = t & 255;
    #pragma unroll
    for (int rnd = 0; rnd < 4; ++rnd) {                  // 4 rounds x 32 nodes
        const int node0 = b * BUCKET_W + rnd * 32 + hh * 16;
        __syncthreads();
        for (int i = tt; i < 512; i += 256) {            // 16 rows x 32 float4
            int r = i >> 5, c4 = i & 31;
            int nr = node0 + r;
            if (nr >= N_NODES) nr = N_NODES - 1;         // bucket 781 tail clamp
            float4 v = *(const float4*)&x[(size_t)nr * D_IN + c4 * 4];
            ushort4 u = make_ushort4(f2bf(v.x), f2bf(v.y), f2bf(v.z), f2bf(v.w));
            *(ushort4*)&sh.xb[hh][r * 136 + c4 * 4] = u;
        }
        __syncthreads();
        f32x4 acc = {0.f, 0.f, 0.f, 0.f};
        #pragma unroll
        for (int ks = 0; ks < 4; ++ks) {
            bf16x8 af = *(const bf16x8*)&sh.xb[hh][m * 136 + 32 * ks + 8 * q];
            acc = __builtin_amdgcn_mfma_f32_16x16x32_bf16(af, bf[ks], acc, 0, 0, 0);
        }
        #pragma unroll
        for (int r = 0; r < 4; ++r) {
            int node = node0 + q * 4 + r;    // C/D: row=(lane>>4)*4+reg, col=lane&15
            if (node < N_NODES) {
                _Float16 hv = (_Float16)(acc[r] * dsh[node - b * BUCKET_W]);
                h_s[node * D_HID + wv * 16 + m] = __builtin_bit_cast(unsigned short, hv);
            }
        }
    }
}

// --- 3. fused aggregate + bias/BN/relu + fc projection (R7-verified) ---
__global__ __launch_bounds__(256) void aggregate_kernel(const ushort* __restrict__ h_s,
                                                        const float* __restrict__ dinv,
                                                        const int2* __restrict__ rs2,
                                                        const int* __restrict__ csr_src,
                                                        const float* __restrict__ b1,
                                                        const float* __restrict__ gamma,
                                                        const float* __restrict__ beta,
                                                        const float* __restrict__ mean,
                                                        const float* __restrict__ var,
                                                        const float* __restrict__ Wfc,
                                                        float4* __restrict__ uv) {
    const f16x8* __restrict__ hsv = (const f16x8*)h_s;   // [node][8] octets
    const int wvid = (blockIdx.x * 256 + threadIdx.x) >> 6; // wave id (grid exact)
    const int lane = threadIdx.x & 63;
    const int oct = lane >> 3;                           // node slot 0..7
    const int ol = lane & 7;                             // feature octet 0..7
    const int n = wvid * 8 + oct;                        // node
    f16x8 acc = hsv[n * 8 + ol];                         // self-loop (pre-scaled)
    const int2 rs = rs2[n];
    const int start = rs.x;
    const int cnt = rs.y;
    int j = 0;
    for (; j + 8 <= cnt; j += 8) {                       // 8 gathers in flight/octet
        int i0 = csr_src[start + j + 0];
        int i1 = csr_src[start + j + 1];
        int i2 = csr_src[start + j + 2];
        int i3 = csr_src[start + j + 3];
        int i4 = csr_src[start + j + 4];
        int i5 = csr_src[start + j + 5];
        int i6 = csr_src[start + j + 6];
        int i7 = csr_src[start + j + 7];
        f16x8 v0 = hsv[i0 * 8 + ol];
        f16x8 v1 = hsv[i1 * 8 + ol];
        f16x8 v2 = hsv[i2 * 8 + ol];
        f16x8 v3 = hsv[i3 * 8 + ol];
        f16x8 v4 = hsv[i4 * 8 + ol];
        f16x8 v5 = hsv[i5 * 8 + ol];
        f16x8 v6 = hsv[i6 * 8 + ol];
        f16x8 v7 = hsv[i7 * 8 + ol];
        acc += v0; acc += v1; acc += v2; acc += v3;
        acc += v4; acc += v5; acc += v6; acc += v7;
    }
    for (; j + 4 <= cnt; j += 4) {
        int i0 = csr_src[start + j + 0];
        int i1 = csr_src[start + j + 1];
        int i2 = csr_src[start + j + 2];
        int i3 = csr_src[start + j + 3];
        f16x8 v0 = hsv[i0 * 8 + ol];
        f16x8 v1 = hsv[i1 * 8 + ol];
        f16x8 v2 = hsv[i2 * 8 + ol];
        f16x8 v3 = hsv[i3 * 8 + ol];
        acc += v0; acc += v1; acc += v2; acc += v3;
    }
    for (; j + 2 <= cnt; j += 2) {
        int i0 = csr_src[start + j + 0];
        int i1 = csr_src[start + j + 1];
        f16x8 v0 = hsv[i0 * 8 + ol];
        f16x8 v1 = hsv[i1 * 8 + ol];
        acc += v0; acc += v1;
    }
    if (j < cnt)
        acc += hsv[csr_src[start + j] * 8 + ol];
    // epilogue: lane handles features f0..f0+7 of node n
    const float dn = dinv[n];
    const int f0 = 8 * ol;
    float a[8];
    #pragma unroll
    for (int k = 0; k < 8; ++k) a[k] = (float)acc[k] * dn;
    float bb[8], mu[8], vr[8], gm[8], bt[8];
    *(float4*)&bb[0] = *(const float4*)&b1[f0];    *(float4*)&bb[4] = *(const float4*)&b1[f0 + 4];
    *(float4*)&mu[0] = *(const float4*)&mean[f0];  *(float4*)&mu[4] = *(const float4*)&mean[f0 + 4];
    *(float4*)&vr[0] = *(const float4*)&var[f0];   *(float4*)&vr[4] = *(const float4*)&var[f0 + 4];
    *(float4*)&gm[0] = *(const float4*)&gamma[f0]; *(float4*)&gm[4] = *(const float4*)&gamma[f0 + 4];
    *(float4*)&bt[0] = *(const float4*)&beta[f0];  *(float4*)&bt[4] = *(const float4*)&beta[f0 + 4];
    #pragma unroll
    for (int k = 0; k < 8; ++k) {
        float v = fmaxf(a[k] + bb[k], 0.f);
        a[k] = fmaxf((v - mu[k]) * rsqrtf(vr[k] + BN_EPS) * gm[k] + bt[k], 0.f);
    }
    // Wfc[128][2]: top rows f0..f0+7 -> p0/p1; bottom rows 64+f0.. -> p2/p3
    float wt[16], wb[16];
    #pragma unroll
    for (int k = 0; k < 4; ++k) {
        *(float4*)&wt[4 * k] = *(const float4*)&Wfc[2 * f0 + 4 * k];
        *(float4*)&wb[4 * k] = *(const float4*)&Wfc[128 + 2 * f0 + 4 * k];
    }
    float p0 = 0.f, p1 = 0.f, p2 = 0.f, p3 = 0.f;
    #pragma unroll
    for (int k = 0; k < 8; ++k) {
        p0 += a[k] * wt[2 * k];
        p1 += a[k] * wt[2 * k + 1];
        p2 += a[k] * wb[2 * k];
        p3 += a[k] * wb[2 * k + 1];
    }
    #pragma unroll
    for (int off = 4; off > 0; off >>= 1) {              // reduce within octet
        p0 += __shfl_xor(p0, off, 64);
        p1 += __shfl_xor(p1, off, 64);
        p2 += __shfl_xor(p2, off, 64);
        p3 += __shfl_xor(p3, off, 64);
    }
    if (ol == 0) uv[n] = make_float4(p0, p1, p2, p3);
}

// --- 4. edge head: 2 edges/thread; out = uv[row].xy + uv[col].zw + bfc ---
__global__ __launch_bounds__(256) void edgeout_kernel(const int* __restrict__ row,
                                                      const int* __restrict__ col,
                                                      const float4* __restrict__ uv,
                                                      const float* __restrict__ bfc,
                                                      float2* __restrict__ out) {
    int i = blockIdx.x * 256 + threadIdx.x;          // over N_EDGES/2 (grid exact)
    int e = i * 2;
    int2 rr = *(const int2*)&row[e];
    int2 cc = *(const int2*)&col[e];
    float4 a0 = uv[rr.x];
    float4 b0 = uv[cc.x];
    float4 a1 = uv[rr.y];
    float4 b1 = uv[cc.y];
    float c0 = bfc[0], c1 = bfc[1];
    float4 o = make_float4(a0.x + b0.z + c0, a0.y + b0.w + c1,
                           a1.x + b1.z + c0, a1.y + b1.w + c1);
    *(float4*)&out[e] = o;
}

extern "C" void kernel_launch(void* const* d_in, const int* in_sizes, int n_in,
                              void* d_out, int out_size, void* d_ws, size_t ws_size,
                              hipStream_t stream) {
    const float* x     = (const float*)d_in[0];
    const int*   ei    = (const int*)d_in[1];
    const int*   row   = ei;             // sources
    const int*   col   = ei + N_EDGES;   // targets
    const float* W1    = (const float*)d_in[2];
    const float* b1    = (const float*)d_in[3];
    const float* gamma = (const float*)d_in[4];
    const float* beta  = (const float*)d_in[5];
    const float* mean  = (const float*)d_in[6];
    const float* var   = (const float*)d_in[7];
    const float* Wfc   = (const float*)d_in[8];
    const float* bfc   = (const float*)d_in[9];
    float2* out = (float2*)d_out;

    char* ws = (char*)d_ws;
    size_t off = 0;
    ushort* h_s      = (ushort*)(ws + off); off += (size_t)N_NODES * D_HID * 2;    // 12.8 MB
    int*   binned    = (int*)(ws + off);    off += (size_t)N_BUCKETS * BCAP * 4;   // 12.8 MB
    int*   csr_src   = (int*)(ws + off);    off += (size_t)N_BUCKETS * BCAP * 4;   // 12.8 MB
    int*   bcursor   = (int*)(ws + off);    off += ((size_t)N_BUCKETS * 4 + 15) & ~(size_t)15;
    int2*  rs2       = (int2*)(ws + off);   off += (size_t)N_NODES * 8;            // 0.8 MB
    float* dinv      = (float*)(ws + off);  off += (size_t)N_NODES * 4;
    float4* uv       = (float4*)(ws + off); off += (size_t)N_NODES * 16;           // 1.6 MB

    hipMemsetAsync(bcursor, 0, N_BUCKETS * sizeof(int), stream);
    bin_scatter_kernel<<<N_BIN_BLOCKS, 1024, 0, stream>>>(row, col, bcursor, binned);
    csr_gemm_kernel<<<N_BUCKETS, 512, 0, stream>>>(binned, bcursor, x, W1,
                                                   csr_src, rs2, dinv, h_s);
    aggregate_kernel<<<N_NODES / 32, 256, 0, stream>>>(h_s, dinv, rs2, csr_src,
                                                       b1, gamma, beta, mean, var,
                                                       Wfc, uv);
    edgeout_kernel<<<N_EDGES / 512, 256, 0, stream>>>(row, col, uv, bfc, out);
}